// Round 8
// baseline (93.916 us; speedup 1.0000x reference)
//
#include <hip/hip_runtime.h>

#define SEQ 8192
#define DIM 128
#define QR  4                          // query rows per wave
#define WPB 8                          // waves per block (512 threads)
#define RPB (QR * WPB)                 // 32 rows per block
#define NB  (2 * SEQ / RPB)            // 512 blocks
#define SROWS 96                       // staged K/V rows: [blkrow0-64, blkrow0+31]

// fp32 in / fp32 out. One wave handles QR=4 consecutive query rows [r0,r0+3];
// lane l owns key j = r0-60+l. Row rr's window is [r0-60, r0+rr] (61..64
// keys); dropped keys carry bias <= -61 -> relative weight < e^-50, invisible
// at fp32. Global sinks (j<100) only matter inside this window (rows i<164).
//
// R8 changes vs R7 (~35us kernel, neutral across 3 memory layouts):
//  * NO cross-lane ops anywhere. Softmax max-reduction replaced by fixed
//    stabilizer M=8 (valid: s <= ~6; l >= e^-14, no underflow; w=e/l exact).
//    Sum-reduction folded into PV: l accumulated from the same LDS-broadcast
//    e values; normalize at the end. Removes 48 serial ds_swizzle/wave
//    (~120cyc latency each -- the suspected ~30us chain).
//  * V staged in LDS alongside K: ALL global reads issue as one coalesced
//    burst before the barrier; PV is pure LDS (contiguous b64, conflict-free)
//    -- removes dependent global-load latency from the PV loop.
//  * q stays scalar-uniform (R6-proven). LDS total 104 KB -> 1 block/CU.
__global__ __launch_bounds__(512) void lminf_kernel(
    const float* __restrict__ qg,
    const float* __restrict__ kg,
    const float* __restrict__ vg,
    float* __restrict__ og)
{
    const int tid  = threadIdx.x;
    const int lane = tid & 63;
    const int wv   = __builtin_amdgcn_readfirstlane(tid >> 6);  // uniform 0..7

    // XCD-contiguity remap (harmless, kept from R7)
    const int wk      = ((blockIdx.x & 7) << 6) + (blockIdx.x >> 3);
    const int rowblk  = wk * RPB + wv * QR;          // wave's first query row
    const int r0      = rowblk & (SEQ - 1);
    const int blkrow0 = (wk * RPB) & (SEQ - 1);      // block's first row
    const long base   = (long)((wk * RPB) >> 13) * (SEQ * DIM);

    __shared__ float4 kds[SROWS * 32];               // 48 KB, chunk c at c^(row&7)
    __shared__ float4 vds[SROWS * 32];               // 48 KB, linear
    __shared__ float4 wsm[WPB][64];                  // 8 KB, per-key packed e

    // ---- burst-stage K (XOR-swizzled) and V (linear), fully coalesced ----
    {
        const float4* kgp = (const float4*)(kg + base);
        const float4* vgp = (const float4*)(vg + base);
        #pragma unroll
        for (int it = 0; it < (SROWS * 32) / 512; ++it) {   // 6 iters
            const int g   = it * 512 + tid;
            const int row = g >> 5;
            const int c   = g & 31;
            int gr = blkrow0 - 64 + row;
            if (gr < 0) gr = 0;                 // clamped rows get weight 0
            kds[row * 32 + (c ^ (row & 7))] = kgp[gr * 32 + c];
            vds[row * 32 + c]               = vgp[gr * 32 + c];
        }
    }
    __syncthreads();

    // ---- QK: K via swizzled ds_read_b128; q via wave-uniform s_load ----
    const int w0 = r0 - 60;                     // key owned by lane 0
    const int j  = w0 + lane;
    const int lr = lane + wv * QR + 4;          // staged local row of key j
    const int sw = lr & 7;
    const float4* krow = &kds[lr * 32];
    const float* qb = qg + base + (long)r0 * DIM;   // wave-uniform

    float acc[QR] = {0.f, 0.f, 0.f, 0.f};
    #pragma unroll 8
    for (int c = 0; c < 32; ++c) {
        const float4 kk = krow[c ^ sw];
        #pragma unroll
        for (int rr = 0; rr < QR; ++rr) {
            const float4 qq = *(const float4*)(qb + rr * DIM + c * 4);
            acc[rr] += qq.x * kk.x + qq.y * kk.y + qq.z * kk.z + qq.w * kk.w;
        }
    }

    // ---- shuffle-free softmax numerator: fixed stabilizer M = 8 ----
    float e[QR];
    #pragma unroll
    for (int rr = 0; rr < QR; ++rr) {
        const int i = r0 + rr;
        float s = acc[rr] * 0.08838834764831845f + (float)(j - i);  // bias
        if (j > i || j < 0) s = -3.0e38f;       // causal + left-edge mask
        e[rr] = __expf(s - 8.0f);               // masked lanes -> exact 0
    }
    // lane k holds key w0+k's numerators; same-wave write->read, no barrier
    wsm[wv][lane] = make_float4(e[0], e[1], e[2], e[3]);

    // ---- PV: pure LDS. V rows contiguous b64; weights uniform broadcast;
    //      row-sum l accumulated from the broadcast values ----
    float o0[QR] = {0.f, 0.f, 0.f, 0.f};
    float o1[QR] = {0.f, 0.f, 0.f, 0.f};
    float lsum[QR] = {0.f, 0.f, 0.f, 0.f};
    #pragma unroll 16
    for (int k = 0; k < 64; ++k) {
        const float2 vpair = *(const float2*)(
            (const float*)&vds[(k + wv * QR + 4) * 32] + 2 * lane);
        const float4 wk4 = wsm[wv][k];          // uniform addr -> broadcast
        lsum[0] += wk4.x;  lsum[1] += wk4.y;
        lsum[2] += wk4.z;  lsum[3] += wk4.w;
        o0[0] += wk4.x * vpair.x;  o1[0] += wk4.x * vpair.y;
        o0[1] += wk4.y * vpair.x;  o1[1] += wk4.y * vpair.y;
        o0[2] += wk4.z * vpair.x;  o1[2] += wk4.z * vpair.y;
        o0[3] += wk4.w * vpair.x;  o1[3] += wk4.w * vpair.y;
    }

    // ---- normalize and store (coalesced float2 per lane per row) ----
    #pragma unroll
    for (int rr = 0; rr < QR; ++rr) {
        const float rl = 1.0f / lsum[rr];       // l >= e^-14 > 0 always
        ((float2*)(og + base + (long)(r0 + rr) * DIM))[lane] =
            make_float2(o0[rr] * rl, o1[rr] * rl);
    }
}

extern "C" void kernel_launch(void* const* d_in, const int* in_sizes, int n_in,
                              void* d_out, int out_size, void* d_ws, size_t ws_size,
                              hipStream_t stream) {
    const float* q = (const float*)d_in[0];
    const float* k = (const float*)d_in[1];
    const float* v = (const float*)d_in[2];
    float* out = (float*)d_out;

    lminf_kernel<<<NB, 512, 0, stream>>>(q, k, v, out);
}